// Round 2
// baseline (53.404 us; speedup 1.0000x reference)
//
#include <hip/hip_runtime.h>
#include <cfloat>

#define B  32
#define C  3
#define H  512
#define W  512
#define HW (H * W)
#define CHW (C * H * W)
#define W4 (W / 4)

// Per-pixel value channel BEFORE quantization: just max over RGB.
// clip+floor are monotone non-decreasing, so they commute with min/max over H
// and are applied once on the combined values in stage 2a.
__device__ __forceinline__ float max3f(float a, float b, float c) {
    return fmaxf(fmaxf(a, b), c);             // fuses to v_max3_f32
}

// Stage 1: per (b, h-chunk), per-column min/max of max-over-RGB for pred & tgt.
// grid = B*HC blocks, 128 threads; lane t owns columns [4t, 4t+3].
__global__ __launch_bounds__(128) void s1_minmax(
        const float* __restrict__ pred, const float* __restrict__ tgt,
        float* __restrict__ ws, int HC, int rows) {
    const int b     = blockIdx.x / HC;
    const int chunk = blockIdx.x - b * HC;
    const int w4    = threadIdx.x;            // 0..127

    const float4* P = reinterpret_cast<const float4*>(pred) + (size_t)b * (CHW / 4);
    const float4* T = reinterpret_cast<const float4*>(tgt)  + (size_t)b * (CHW / 4);

    float4 mnP = make_float4( FLT_MAX,  FLT_MAX,  FLT_MAX,  FLT_MAX);
    float4 mxP = make_float4(-FLT_MAX, -FLT_MAX, -FLT_MAX, -FLT_MAX);
    float4 mnT = mnP;
    float4 mxT = mxP;

    const int h0 = chunk * rows;
    #pragma unroll 4
    for (int h = h0; h < h0 + rows; ++h) {
        const int base = h * W4 + w4;
        // prediction: 3 channels
        float4 a  = P[base];
        float4 g  = P[base +     (HW / 4)];
        float4 c2 = P[base + 2 * (HW / 4)];
        float v0 = max3f(a.x, g.x, c2.x);
        float v1 = max3f(a.y, g.y, c2.y);
        float v2 = max3f(a.z, g.z, c2.z);
        float v3 = max3f(a.w, g.w, c2.w);
        mnP.x = fminf(mnP.x, v0); mxP.x = fmaxf(mxP.x, v0);
        mnP.y = fminf(mnP.y, v1); mxP.y = fmaxf(mxP.y, v1);
        mnP.z = fminf(mnP.z, v2); mxP.z = fmaxf(mxP.z, v2);
        mnP.w = fminf(mnP.w, v3); mxP.w = fmaxf(mxP.w, v3);
        // target: 3 channels
        a  = T[base];
        g  = T[base +     (HW / 4)];
        c2 = T[base + 2 * (HW / 4)];
        v0 = max3f(a.x, g.x, c2.x);
        v1 = max3f(a.y, g.y, c2.y);
        v2 = max3f(a.z, g.z, c2.z);
        v3 = max3f(a.w, g.w, c2.w);
        mnT.x = fminf(mnT.x, v0); mxT.x = fmaxf(mxT.x, v0);
        mnT.y = fminf(mnT.y, v1); mxT.y = fmaxf(mxT.y, v1);
        mnT.z = fminf(mnT.z, v2); mxT.z = fmaxf(mxT.z, v2);
        mnT.w = fminf(mnT.w, v3); mxT.w = fmaxf(mxT.w, v3);
    }

    // ws layout: 4 arrays of [B][HC][W] floats: minP, maxP, minT, maxT
    const size_t arr = (size_t)B * HC * W4;   // in float4 units
    const size_t o   = ((size_t)b * HC + chunk) * W4 + w4;
    float4* wsv = reinterpret_cast<float4*>(ws);
    wsv[o]           = mnP;
    wsv[o + arr]     = mxP;
    wsv[o + 2 * arr] = mnT;
    wsv[o + 3 * arr] = mxT;
}

__device__ __forceinline__ float qclip(float m) {
    return floorf(fminf(fmaxf(m, 0.0f), 255.0f));   // clamp -> med3, then floor
}

// Stage 2a: combine chunk partials per (b,w), clip+floor, squared diffs,
// block tree-reduce. grid = 256 blocks x 256 threads; 4 threads per (b,w)
// pair split the HC loop; 64 pairs per block.
__global__ __launch_bounds__(256) void s2a_reduce(
        const float* __restrict__ ws, double* __restrict__ partial, int HC) {
    const int p  = threadIdx.x & 63;            // pair-in-block
    const int q  = threadIdx.x >> 6;            // quarter 0..3
    const int i  = blockIdx.x * 64 + p;         // pair 0..16383
    const int b  = i / W;
    const int w  = i - b * W;
    const int QC = HC >> 2;                     // HC is a power of two >= 4

    const size_t arr = (size_t)B * HC * W;
    const float* minP = ws;
    const float* maxP = ws + arr;
    const float* minT = ws + 2 * arr;
    const float* maxT = ws + 3 * arr;

    float mnP = FLT_MAX, mxP = -FLT_MAX, mnT = FLT_MAX, mxT = -FLT_MAX;
    const int c0 = q * QC;
    for (int c = c0; c < c0 + QC; ++c) {
        const size_t o = ((size_t)b * HC + c) * W + w;
        mnP = fminf(mnP, minP[o]);
        mxP = fmaxf(mxP, maxP[o]);
        mnT = fminf(mnT, minT[o]);
        mxT = fmaxf(mxT, maxT[o]);
    }

    __shared__ float4 s4[256];
    s4[threadIdx.x] = make_float4(mnP, mxP, mnT, mxT);
    __syncthreads();

    __shared__ double sd[64];
    if (q == 0) {
        float4 v0 = s4[p], v1 = s4[p + 64], v2 = s4[p + 128], v3 = s4[p + 192];
        float fmnP = fminf(fminf(v0.x, v1.x), fminf(v2.x, v3.x));
        float fmxP = fmaxf(fmaxf(v0.y, v1.y), fmaxf(v2.y, v3.y));
        float fmnT = fminf(fminf(v0.z, v1.z), fminf(v2.z, v3.z));
        float fmxT = fmaxf(fmaxf(v0.w, v1.w), fmaxf(v2.w, v3.w));
        const float dmin = qclip(fmnP) - qclip(fmnT);
        const float dmax = qclip(fmxP) - qclip(fmxT);
        sd[p] = (double)dmin * (double)dmin + (double)dmax * (double)dmax;
    }
    __syncthreads();
    for (int st = 32; st > 0; st >>= 1) {
        if (threadIdx.x < st) sd[threadIdx.x] += sd[threadIdx.x + st];
        __syncthreads();
    }
    if (threadIdx.x == 0) partial[blockIdx.x] = sd[0];
}

// Stage 2b: sum 256 partials, write mean-sum scalar.
__global__ __launch_bounds__(256) void s2b_final(
        const double* __restrict__ partial, float* __restrict__ out) {
    __shared__ double sd[256];
    sd[threadIdx.x] = partial[threadIdx.x];
    __syncthreads();
    for (int st = 128; st > 0; st >>= 1) {
        if (threadIdx.x < st) sd[threadIdx.x] += sd[threadIdx.x + st];
        __syncthreads();
    }
    if (threadIdx.x == 0) out[0] = (float)(sd[0] / (double)(B * W));
}

extern "C" void kernel_launch(void* const* d_in, const int* in_sizes, int n_in,
                              void* d_out, int out_size, void* d_ws, size_t ws_size,
                              hipStream_t stream) {
    const float* pred = (const float*)d_in[0];
    const float* tgt  = (const float*)d_in[1];
    float* out = (float*)d_out;
    float* wsf = (float*)d_ws;

    // Largest power-of-two chunk count (>=4) whose partials fit in ws.
    int HC = 128;
    while (HC > 4 &&
           (size_t)4 * B * HC * W * sizeof(float) + 256 * sizeof(double) > ws_size) {
        HC >>= 1;
    }
    const int rows = H / HC;

    hipLaunchKernelGGL(s1_minmax, dim3(B * HC), dim3(128), 0, stream,
                       pred, tgt, wsf, HC, rows);

    double* partial = (double*)(wsf + (size_t)4 * B * HC * W);
    hipLaunchKernelGGL(s2a_reduce, dim3(256), dim3(256), 0, stream,
                       wsf, partial, HC);
    hipLaunchKernelGGL(s2b_final, dim3(1), dim3(256), 0, stream,
                       partial, out);
}

// Round 4
// 40.271 us; speedup vs baseline: 1.3261x; 1.3261x over previous
//
#include <hip/hip_runtime.h>
#include <cfloat>

#define B_   32
#define H_   512
#define W_   512
#define HW_  (H_ * W_)
#define CHW_ (3 * HW_)
#define W4_  (W_ / 4)
#define HC_  16                 // h-chunks per image
#define ROWS_ (H_ / HC_)        // 32 rows per chunk

__device__ __forceinline__ float max3f(float a, float b, float c) {
    return fmaxf(fmaxf(a, b), c);             // fuses to v_max3_f32
}
__device__ __forceinline__ float4 min4(float4 a, float4 b) {
    return make_float4(fminf(a.x, b.x), fminf(a.y, b.y), fminf(a.z, b.z), fminf(a.w, b.w));
}
__device__ __forceinline__ float4 max4(float4 a, float4 b) {
    return make_float4(fmaxf(a.x, b.x), fmaxf(a.y, b.y), fmaxf(a.z, b.z), fmaxf(a.w, b.w));
}
// clip+floor are monotone -> commute with min/max over H; applied in s2a.
// (verified exact vs reference in round 2)
__device__ __forceinline__ float qclip(float m) {
    return floorf(fminf(fmaxf(m, 0.0f), 255.0f));
}

// Stage 1: ONE input per block (3 read streams/wave instead of 6).
// grid = 2*B*HC blocks x 128 threads; low bit of blockIdx selects pred/tgt.
__global__ __launch_bounds__(128) void s1_minmax(
        const float* __restrict__ pred, const float* __restrict__ tgt,
        float* __restrict__ ws) {
    const int inp   = blockIdx.x & 1;
    const int bc    = blockIdx.x >> 1;            // 0..511
    const int b     = bc >> 4;
    const int chunk = bc & (HC_ - 1);
    const int w4    = threadIdx.x;                // 0..127

    const float4* S = reinterpret_cast<const float4*>(inp ? tgt : pred)
                      + (size_t)b * (CHW_ / 4);

    float4 mn = make_float4( FLT_MAX,  FLT_MAX,  FLT_MAX,  FLT_MAX);
    float4 mx = make_float4(-FLT_MAX, -FLT_MAX, -FLT_MAX, -FLT_MAX);

    const int h0 = chunk * ROWS_;
    #pragma unroll 8
    for (int h = h0; h < h0 + ROWS_; ++h) {
        const int base = h * W4_ + w4;
        float4 a  = S[base];
        float4 g  = S[base +      (HW_ / 4)];
        float4 c2 = S[base + 2 * (HW_ / 4)];
        float4 v = make_float4(max3f(a.x, g.x, c2.x), max3f(a.y, g.y, c2.y),
                               max3f(a.z, g.z, c2.z), max3f(a.w, g.w, c2.w));
        mn = min4(mn, v);
        mx = max4(mx, v);
    }

    // ws layout: 4 arrays of [B][HC][W] floats: minP, maxP, minT, maxT
    const size_t arr = (size_t)B_ * HC_ * W4_;    // float4 units
    const size_t o   = ((size_t)b * HC_ + chunk) * W4_ + w4;
    float4* wsv = reinterpret_cast<float4*>(ws);
    wsv[o + (size_t)(2 * inp + 0) * arr] = mn;    // minP / minT
    wsv[o + (size_t)(2 * inp + 1) * arr] = mx;    // maxP / maxT
}

// Stage 2a: combine chunk partials per (b,w), clip+floor, squared diffs,
// block tree-reduce. grid = 64 blocks x 256 threads; one thread per (b,w).
__global__ __launch_bounds__(256) void s2a_reduce(
        const float* __restrict__ ws, double* __restrict__ partial) {
    const int i = blockIdx.x * 256 + threadIdx.x;   // 0..16383
    const int b = i >> 9;
    const int w = i & (W_ - 1);

    const size_t arr = (size_t)B_ * HC_ * W_;
    const float* minP = ws;
    const float* maxP = ws + arr;
    const float* minT = ws + 2 * arr;
    const float* maxT = ws + 3 * arr;

    float mnP = FLT_MAX, mxP = -FLT_MAX, mnT = FLT_MAX, mxT = -FLT_MAX;
    #pragma unroll 4
    for (int c = 0; c < HC_; ++c) {
        const size_t o = ((size_t)b * HC_ + c) * W_ + w;
        mnP = fminf(mnP, minP[o]);
        mxP = fmaxf(mxP, maxP[o]);
        mnT = fminf(mnT, minT[o]);
        mxT = fmaxf(mxT, maxT[o]);
    }
    const float dmin = qclip(mnP) - qclip(mnT);
    const float dmax = qclip(mxP) - qclip(mxT);
    double s = (double)dmin * (double)dmin + (double)dmax * (double)dmax;

    __shared__ double sd[256];
    sd[threadIdx.x] = s;
    __syncthreads();
    #pragma unroll
    for (int st = 128; st > 0; st >>= 1) {
        if (threadIdx.x < st) sd[threadIdx.x] += sd[threadIdx.x + st];
        __syncthreads();
    }
    if (threadIdx.x == 0) partial[blockIdx.x] = sd[0];
}

// Stage 2b: sum 64 partials, write mean-sum scalar.
__global__ __launch_bounds__(64) void s2b_final(
        const double* __restrict__ partial, float* __restrict__ out) {
    __shared__ double sd[64];
    sd[threadIdx.x] = partial[threadIdx.x];
    __syncthreads();
    #pragma unroll
    for (int st = 32; st > 0; st >>= 1) {
        if (threadIdx.x < st) sd[threadIdx.x] += sd[threadIdx.x + st];
        __syncthreads();
    }
    if (threadIdx.x == 0) out[0] = (float)(sd[0] / (double)(B_ * W_));
}

extern "C" void kernel_launch(void* const* d_in, const int* in_sizes, int n_in,
                              void* d_out, int out_size, void* d_ws, size_t ws_size,
                              hipStream_t stream) {
    const float* pred = (const float*)d_in[0];
    const float* tgt  = (const float*)d_in[1];
    float* out = (float*)d_out;
    float* wsf = (float*)d_ws;
    double* partial = (double*)(wsf + (size_t)4 * B_ * HC_ * W_);  // after 4.19 MB

    hipLaunchKernelGGL(s1_minmax, dim3(2 * B_ * HC_), dim3(128), 0, stream,
                       pred, tgt, wsf);
    hipLaunchKernelGGL(s2a_reduce, dim3(64), dim3(256), 0, stream,
                       wsf, partial);
    hipLaunchKernelGGL(s2b_final, dim3(1), dim3(64), 0, stream,
                       partial, out);
}